// Round 10
// baseline (262.936 us; speedup 1.0000x reference)
//
#include <hip/hip_runtime.h>
#include <stdint.h>

#define SX 2048
#define SYY 2048
#define DDIM 1024
#define NBATCH 8

typedef _Float16 f16;
typedef __attribute__((ext_vector_type(2))) _Float16 h2_t;
typedef __attribute__((ext_vector_type(4))) _Float16 h4_t;
typedef __attribute__((ext_vector_type(8))) _Float16 h8_t;
typedef __attribute__((ext_vector_type(4))) float fx4_t;

__device__ __forceinline__ void gload_lds16(const void* g, void* l) {
  __builtin_amdgcn_global_load_lds((const __attribute__((address_space(1))) void*)g,
                                   (__attribute__((address_space(3))) void*)l,
                                   16, 0, 0);
}

// ---- prep: copy x into out[:, :, 0:D] (fp32) AND convert x -> fp16 ----
__global__ __launch_bounds__(256) void k_prep_x(const float4* __restrict__ x,
                                                float* __restrict__ out,
                                                h4_t* __restrict__ x16, long n4) {
  long i = (long)blockIdx.x * blockDim.x + threadIdx.x;
  long stride = (long)gridDim.x * blockDim.x;
  for (; i < n4; i += stride) {
    long bi = i >> 8;            // / (DDIM/4)
    int dq = (int)(i & 255);
    float4 v = x[i];
    *(float4*)(out + bi * (2 * DDIM) + dq * 4) = v;
    h4_t h = { (f16)v.x, (f16)v.y, (f16)v.z, (f16)v.w };
    x16[i] = h;
  }
}

// ---- y[z][j][d] fp32 -> Y16[z][j][d] fp16 and Yt16[z][d][j] fp16 ----
__global__ __launch_bounds__(256) void k_trans(const float* __restrict__ y,
                                               f16* __restrict__ y16,
                                               f16* __restrict__ yt16) {
  __shared__ f16 tile[64][72];
  int z = blockIdx.z;
  int d0 = blockIdx.x * 64, j0 = blockIdx.y * 64;
  const float* yb = y + (size_t)z * SYY * DDIM;
  f16* y16b = y16 + (size_t)z * SYY * DDIM;
  f16* ytb = yt16 + (size_t)z * DDIM * SYY;
  int t = threadIdx.x;
  int jl = t >> 2;
  int dq = t & 3;
#pragma unroll
  for (int s = 0; s < 4; ++s) {
    int dl = dq * 16 + s * 4;
    float4 v = *(const float4*)(yb + (size_t)(j0 + jl) * DDIM + d0 + dl);
    h4_t h = { (f16)v.x, (f16)v.y, (f16)v.z, (f16)v.w };
    *(h4_t*)(y16b + (size_t)(j0 + jl) * DDIM + d0 + dl) = h;
    *(h4_t*)&tile[jl][dl] = h;
  }
  __syncthreads();
  int dl2 = t >> 2;
  int jq = t & 3;
  f16 vbuf[16] __attribute__((aligned(16)));
#pragma unroll
  for (int u = 0; u < 16; ++u) vbuf[u] = tile[jq * 16 + u][dl2];
  f16* orow = ytb + (size_t)(d0 + dl2) * SYY + j0 + jq * 16;
  *(uint4*)orow = *(const uint4*)&vbuf[0];
  *(uint4*)(orow + 8) = *(const uint4*)&vbuf[8];
}

// ==== shared 256x256 8-phase GEMM machinery (round-3 verified ledger) ====
#define PH_BAR() __builtin_amdgcn_s_barrier()

#define STAGE_A(SLOT, HALF, T) {                                               \
    const f16* s_ = aRow + (size_t)((HALF) * 64) * lda + (T) * 64;             \
    f16* d_ = lds + (SLOT) * 8192 + dstoff;                                    \
    gload_lds16(s_, d_);                                                       \
    gload_lds16(s_ + (size_t)128 * lda, d_ + 4096); }

#define STAGE_B(SLOT, HALF, T) {                                               \
    const f16* s_ = bRow + (size_t)((HALF) * 32) * ldb + (T) * 64;             \
    f16* d_ = lds + (SLOT) * 8192 + dstoff;                                    \
    gload_lds16(s_, d_);                                                       \
    gload_lds16(s_ + (size_t)128 * ldb, d_ + 4096); }

#define RD_A(PTR, CB) { _Pragma("unroll") for (int i_ = 0; i_ < 4; ++i_) {     \
    af[i_][0] = *(const h8_t*)((PTR) + (CB) + i_ * 2048 + kb0);                \
    af[i_][1] = *(const h8_t*)((PTR) + (CB) + i_ * 2048 + kb1); } }

// gemm2 variant: scale A-fragments by per-row per-K-tile factor FD[MOFF + i]
#define RD_A_S(PTR, CB, MOFF, FD) { _Pragma("unroll") for (int i_ = 0; i_ < 4; ++i_) { \
    h8_t a0 = *(const h8_t*)((PTR) + (CB) + i_ * 2048 + kb0);                  \
    h8_t a1 = *(const h8_t*)((PTR) + (CB) + i_ * 2048 + kb1);                  \
    h2_t* p0 = (h2_t*)&a0; h2_t* p1 = (h2_t*)&a1;                              \
    _Pragma("unroll") for (int q_ = 0; q_ < 4; ++q_) {                         \
      p0[q_] *= FD[(MOFF) + i_]; p1[q_] *= FD[(MOFF) + i_]; }                  \
    af[i_][0] = a0; af[i_][1] = a1; } }

#define RD_B(PTR, CB, NH) { _Pragma("unroll") for (int j_ = 0; j_ < 2; ++j_) { \
    bf[(NH) + j_][0] = *(const h8_t*)((PTR) + (CB) + j_ * 2048 + kb0);         \
    bf[(NH) + j_][1] = *(const h8_t*)((PTR) + (CB) + j_ * 2048 + kb1); } }

#define MM(MH, NH) { __builtin_amdgcn_s_setprio(1);                            \
  _Pragma("unroll") for (int i_ = 0; i_ < 4; ++i_)                             \
  _Pragma("unroll") for (int j_ = 0; j_ < 2; ++j_) {                           \
    acc[(MH) + i_][(NH) + j_] = __builtin_amdgcn_mfma_f32_16x16x32_f16(        \
        af[i_][0], bf[(NH) + j_][0], acc[(MH) + i_][(NH) + j_], 0, 0, 0);      \
    acc[(MH) + i_][(NH) + j_] = __builtin_amdgcn_mfma_f32_16x16x32_f16(        \
        af[i_][1], bf[(NH) + j_][1], acc[(MH) + i_][(NH) + j_], 0, 0, 0); }    \
  __builtin_amdgcn_s_setprio(0); }

// tile-id decode with XCD chunking + n-major half-m ordering for L2 reuse
#define DECODE_TILE()                                                          \
  int bid = blockIdx.x;                                                        \
  int id = bid;                                                                \
  if ((nblk & 7) == 0) { int cpx = nblk >> 3; id = (bid & 7) * cpx + (bid >> 3); } \
  int tpz = ntm * ntn;                                                         \
  int z = id / tpz;                                                            \
  int rem = id - z * tpz;                                                      \
  int mt, ntl;                                                                 \
  if ((ntm & 1) == 0) {                                                        \
    int ht = tpz >> 1, hm = ntm >> 1;                                          \
    int half = rem / ht, j = rem - half * ht;                                  \
    ntl = j / hm; mt = half * hm + (j - ntl * hm);                             \
  } else { mt = rem / ntn; ntl = rem - mt * ntn; }                             \
  int m0 = mt * 256, n0 = ntl * 256;

#define GEMM_COMMON_SETUP()                                                    \
  const int tid = threadIdx.x;                                                 \
  const int lane = tid & 63, w = tid >> 6;                                     \
  const int wr = w >> 2, wc = w & 3;                                           \
  const int fr = lane & 15, fh = lane >> 4;                                    \
  const f16* Ab = A + (size_t)z * a_zs + (size_t)(a_row0 + m0) * lda;          \
  const f16* Bb = B + (size_t)z * b_zs + (size_t)n0 * ldb;                     \
  const int l0 = 8 * w + (lane >> 3);                                          \
  const int r0a = l0;                                                          \
  const int r0b = ((l0 >> 5) << 6) | (l0 & 31);                                \
  const int swz = 8 * ((lane & 7) ^ (lane >> 3));                              \
  const f16* aRow = Ab + (size_t)r0a * lda + swz;                              \
  const f16* bRow = Bb + (size_t)r0b * ldb + swz;                              \
  const int dstoff = w * 512 + lane * 8;                                       \
  const char* ldsAlo = (const char*)lds + wr * 8192 + fr * 128;                \
  const char* ldsAhi = ldsAlo + 16384;                                         \
  const char* ldsBlo = (const char*)lds + 32768 + wc * 4096 + fr * 128;        \
  const char* ldsBhi = ldsBlo + 16384;                                         \
  const int kb0 = ((0 + fh) ^ (fr & 7)) * 16;                                  \
  const int kb1 = ((4 + fh) ^ (fr & 7)) * 16;

// ==== GEMM1: S = X16 . Y16^T, barrier-free per-wave softmax epilogue ====
// u = exp(s - m_quarter) per 64-col quarter; (m,l) emitted per (row,tile,wc).
__global__ __launch_bounds__(512, 2) void k_gemm1(
    const f16* __restrict__ A, long a_zs, int a_row0, int lda,
    const f16* __restrict__ B, long b_zs, int ldb,
    f16* __restrict__ U, long u_zs,
    float2* __restrict__ ML, int mrows,
    int K, int ntm, int ntn, int nblk)
{
  __shared__ f16 lds[65536];
  DECODE_TILE();
  GEMM_COMMON_SETUP();

  const int nt = K >> 6;
  const int ng = nt >> 1;

  fx4_t acc[8][4];
#pragma unroll
  for (int i = 0; i < 8; ++i)
#pragma unroll
    for (int j = 0; j < 4; ++j) { fx4_t zv = {0.f,0.f,0.f,0.f}; acc[i][j] = zv; }
  h8_t af[4][2], bf[4][2];

  STAGE_A(0, 0, 0); STAGE_A(1, 1, 0); STAGE_B(2, 0, 0); STAGE_B(3, 1, 0);
  STAGE_A(4, 0, 1); STAGE_B(6, 0, 1); STAGE_B(7, 1, 1);
  asm volatile("s_waitcnt vmcnt(6)" ::: "memory");
  PH_BAR();

  for (int g = 0; g < ng; ++g) {
    const int T1 = 2 * g + 1, T2 = 2 * g + 2, T3 = 2 * g + 3;
    const bool nl = (g < ng - 1);
    RD_A(ldsAlo, 0); RD_B(ldsBlo, 0, 0);
    STAGE_A(5, 1, T1);
    PH_BAR();
    MM(0, 0);
    PH_BAR();
    RD_B(ldsBhi, 0, 2);
    if (nl) STAGE_A(0, 0, T2);
    PH_BAR();
    MM(0, 2);
    PH_BAR();
    RD_A(ldsAhi, 0);
    if (nl) STAGE_B(2, 0, T2);
    PH_BAR();
    MM(4, 0);
    PH_BAR();
    if (nl) STAGE_B(3, 1, T2);
    PH_BAR();
    MM(4, 2);
    if (nl) { asm volatile("s_waitcnt vmcnt(6)" ::: "memory"); }
    else    { asm volatile("s_waitcnt vmcnt(0)" ::: "memory"); }
    PH_BAR();
    RD_A(ldsAlo, 65536); RD_B(ldsBlo, 65536, 0);
    if (nl) STAGE_A(1, 1, T2);
    PH_BAR();
    MM(0, 0);
    PH_BAR();
    RD_B(ldsBhi, 65536, 2);
    if (nl) STAGE_A(4, 0, T3);
    PH_BAR();
    MM(0, 2);
    PH_BAR();
    RD_A(ldsAhi, 65536);
    if (nl) STAGE_B(6, 0, T3);
    PH_BAR();
    MM(4, 0);
    PH_BAR();
    if (nl) STAGE_B(7, 1, T3);
    PH_BAR();
    MM(4, 2);
    asm volatile("s_waitcnt vmcnt(6)" ::: "memory");
    PH_BAR();
  }

  // ---- barrier-free per-wave epilogue: quarter softmax + scalar U stores ----
  const int rbase = wr * 128 + fh * 4;
  f16* Ub = U + (size_t)z * u_zs;
  // ML layout: [z][ntl(8)][wc(4)][mrows]
  float2* MLp = ML + (((size_t)z * 8 + (n0 >> 8)) * 4 + wc) * mrows + m0;
#pragma unroll
  for (int mi = 0; mi < 8; ++mi)
#pragma unroll
    for (int rr = 0; rr < 4; ++rr) {
      float am = fmaxf(fmaxf(acc[mi][0][rr], acc[mi][1][rr]),
                       fmaxf(acc[mi][2][rr], acc[mi][3][rr]));
      am = fmaxf(am, __shfl_xor(am, 1)); am = fmaxf(am, __shfl_xor(am, 2));
      am = fmaxf(am, __shfl_xor(am, 4)); am = fmaxf(am, __shfl_xor(am, 8));
      float s = 0.f;
#pragma unroll
      for (int ni = 0; ni < 4; ++ni) {
        float e = __expf(acc[mi][ni][rr] - am);
        acc[mi][ni][rr] = e; s += e;
      }
      s += __shfl_xor(s, 1); s += __shfl_xor(s, 2);
      s += __shfl_xor(s, 4); s += __shfl_xor(s, 8);
      int row = rbase + mi * 16 + rr;
      if (fr == 0) { float2 v; v.x = am; v.y = s; MLp[row] = v; }
#pragma unroll
      for (int ni = 0; ni < 4; ++ni)
        Ub[(size_t)(m0 + row) * SYY + n0 + wc * 64 + ni * 16 + fr] =
            (f16)acc[mi][ni][rr];
    }
}

// ---- per-row combine: 32 quarter (m,l) -> factor per 64-col block (f16) ----
__global__ __launch_bounds__(256) void k_mlred(const float2* __restrict__ ML,
                                               f16* __restrict__ Fq,
                                               int rows, long total) {
  long idx = (long)blockIdx.x * blockDim.x + threadIdx.x;
  if (idx >= total) return;
  int z = (int)(idx / rows);
  int r = (int)(idx - (long)z * rows);
  float M = -3.4e38f;
  float2 v[32];
#pragma unroll
  for (int t = 0; t < 32; ++t) {
    v[t] = ML[((size_t)z * 32 + t) * rows + r];
    M = fmaxf(M, v[t].x);
  }
  float L = 0.f;
#pragma unroll
  for (int t = 0; t < 32; ++t) L += v[t].y * __expf(v[t].x - M);
  float inv = 1.0f / L;
#pragma unroll
  for (int t = 0; t < 32; ++t)
    Fq[((size_t)z * 32 + t) * rows + r] = (f16)(__expf(v[t].x - M) * inv);
}

// ==== GEMM2: out_right = (u * factor) . Yt^T, per-K-tile factor on A-frags ====
__global__ __launch_bounds__(512, 2) void k_gemm2(
    const f16* __restrict__ A, long a_zs, int a_row0, int lda,
    const f16* __restrict__ B, long b_zs, int ldb,
    float* __restrict__ C, long c_zs, int c_row0, int ldc, int c_col0,
    const f16* __restrict__ Fq, int mrows,
    int K, int ntm, int ntn, int nblk)
{
  __shared__ f16 lds[65536];
  DECODE_TILE();
  GEMM_COMMON_SETUP();

  const int nt = K >> 6;
  const int ng = nt >> 1;

  fx4_t acc[8][4];
#pragma unroll
  for (int i = 0; i < 8; ++i)
#pragma unroll
    for (int j = 0; j < 4; ++j) { fx4_t zv = {0.f,0.f,0.f,0.f}; acc[i][j] = zv; }
  h8_t af[4][2], bf[4][2];

  // factor table [z][t64(32)][mrows]; row(mi) = m0 + wr*128 + mi*16 + fr
  const f16* Fb = Fq + (size_t)z * 32 * mrows + m0 + wr * 128 + fr;
  h2_t fcA[8], fcB[8], fnA[8], fnB[8];
  // preload factors for k-tiles 0 and 1
#pragma unroll
  for (int i = 0; i < 8; ++i) {
    f16 a = Fb[i * 16], b = Fb[(size_t)mrows + i * 16];
    h2_t da; da[0] = a; da[1] = a; fnA[i] = da;
    h2_t db; db[0] = b; db[1] = b; fnB[i] = db;
  }

  STAGE_A(0, 0, 0); STAGE_A(1, 1, 0); STAGE_B(2, 0, 0); STAGE_B(3, 1, 0);
  STAGE_A(4, 0, 1); STAGE_B(6, 0, 1); STAGE_B(7, 1, 1);
  asm volatile("s_waitcnt vmcnt(6)" ::: "memory");
  PH_BAR();

  for (int g = 0; g < ng; ++g) {
    const int T1 = 2 * g + 1, T2 = 2 * g + 2, T3 = 2 * g + 3;
    const bool nl = (g < ng - 1);
#pragma unroll
    for (int i = 0; i < 8; ++i) { fcA[i] = fnA[i]; fcB[i] = fnB[i]; }
    RD_A_S(ldsAlo, 0, 0, fcA); RD_B(ldsBlo, 0, 0);
    STAGE_A(5, 1, T1);
    PH_BAR(); MM(0, 0); PH_BAR();
    RD_B(ldsBhi, 0, 2);
    if (nl) STAGE_A(0, 0, T2);
    PH_BAR(); MM(0, 2); PH_BAR();
    RD_A_S(ldsAhi, 0, 4, fcA);
    if (nl) STAGE_B(2, 0, T2);
    PH_BAR(); MM(4, 0); PH_BAR();
    if (nl) STAGE_B(3, 1, T2);
    PH_BAR(); MM(4, 2);
    if (nl) { asm volatile("s_waitcnt vmcnt(6)" ::: "memory"); }
    else    { asm volatile("s_waitcnt vmcnt(0)" ::: "memory"); }
    PH_BAR();
    // ph4: next-group factor prefetch AFTER the checkpoint (ledger position
    // identical to r6's verified prefetch slot)
    RD_A_S(ldsAlo, 65536, 0, fcB); RD_B(ldsBlo, 65536, 0);
    if (nl) {
      const f16* Fn = Fb + (size_t)(2 * g + 2) * mrows;
#pragma unroll
      for (int i = 0; i < 8; ++i) {
        f16 a = Fn[i * 16], b = Fn[(size_t)mrows + i * 16];
        h2_t da; da[0] = a; da[1] = a; fnA[i] = da;
        h2_t db; db[0] = b; db[1] = b; fnB[i] = db;
      }
    }
    if (nl) STAGE_A(1, 1, T2);
    PH_BAR(); MM(0, 0); PH_BAR();
    RD_B(ldsBhi, 65536, 2);
    if (nl) STAGE_A(4, 0, T3);
    PH_BAR(); MM(0, 2); PH_BAR();
    RD_A_S(ldsAhi, 65536, 4, fcB);
    if (nl) STAGE_B(6, 0, T3);
    PH_BAR(); MM(4, 0); PH_BAR();
    if (nl) STAGE_B(7, 1, T3);
    PH_BAR(); MM(4, 2);
    asm volatile("s_waitcnt vmcnt(6)" ::: "memory");
    PH_BAR();
  }

  float* Cb = C + (size_t)z * c_zs +
              (size_t)(c_row0 + m0 + wr * 128) * ldc + c_col0 + n0 + wc * 64;
#pragma unroll
  for (int mi = 0; mi < 8; ++mi)
#pragma unroll
    for (int ni = 0; ni < 4; ++ni)
#pragma unroll
      for (int r = 0; r < 4; ++r)
        Cb[(size_t)(mi * 16 + fh * 4 + r) * ldc + ni * 16 + fr] = acc[mi][ni][r];
}

extern "C" void kernel_launch(void* const* d_in, const int* in_sizes, int n_in,
                              void* d_out, int out_size, void* d_ws, size_t ws_size,
                              hipStream_t stream) {
  (void)in_sizes; (void)n_in; (void)out_size;
  const float* x = (const float*)d_in[0];
  const float* y = (const float*)d_in[1];
  float* out = (float*)d_out;

  // ws per group: U(f16) | ML(float2 x32) | Fq(f16 x32) | X16 | Y16 | Yt16
  size_t per_batch = (size_t)SX * SYY * 2 + (size_t)32 * SX * 8 + (size_t)32 * SX * 2 +
                     (size_t)SX * DDIM * 2 + (size_t)SYY * DDIM * 2 +
                     (size_t)DDIM * SYY * 2;
  int nb = (int)(ws_size / per_batch);
  if (nb > NBATCH) nb = NBATCH;
  int CH = SX;
  if (nb < 1) {
    nb = 1;
    size_t conv = (size_t)SX * DDIM * 2 + (size_t)SYY * DDIM * 2 +
                  (size_t)DDIM * SYY * 2;
    size_t avail = ws_size > conv ? ws_size - conv : 0;
    long ch = (long)(avail / ((size_t)SYY * 2 + 320));
    ch = (ch / 256) * 256;
    if (ch < 256) ch = 256;
    if (ch > SX) ch = SX;
    CH = (int)ch;
  }

  char* w = (char*)d_ws;
  f16* Ubuf = (f16*)w;            size_t off = (size_t)nb * CH * SYY * 2;
  float2* MLbuf = (float2*)(w + off); off += (size_t)nb * 32 * CH * 8;
  f16* Fqbuf = (f16*)(w + off);   off += (size_t)nb * 32 * CH * 2;
  f16* X16 = (f16*)(w + off);     off += (size_t)nb * SX * DDIM * 2;
  f16* Y16 = (f16*)(w + off);     off += (size_t)nb * SYY * DDIM * 2;
  f16* Yt16 = (f16*)(w + off);

  for (int b0 = 0; b0 < NBATCH; b0 += nb) {
    int nbc = (NBATCH - b0 < nb) ? (NBATCH - b0) : nb;
    k_prep_x<<<2048, 256, 0, stream>>>(
        (const float4*)(x + (size_t)b0 * SX * DDIM),
        out + (size_t)b0 * SX * 2 * DDIM, (h4_t*)X16,
        (long)nbc * SX * (DDIM / 4));
    dim3 tg(DDIM / 64, SYY / 64, nbc);
    k_trans<<<tg, 256, 0, stream>>>(y + (size_t)b0 * SYY * DDIM, Y16, Yt16);

    for (int i0 = 0; i0 < SX; i0 += CH) {
      int ntm = CH / 256;
      int nblk1 = nbc * ntm * (SYY / 256);
      k_gemm1<<<nblk1, 512, 0, stream>>>(X16, (long)SX * DDIM, i0, DDIM,
                                         Y16, (long)SYY * DDIM, DDIM,
                                         Ubuf, (long)CH * SYY,
                                         MLbuf, CH,
                                         DDIM, ntm, SYY / 256, nblk1);
      long rows_total = (long)nbc * CH;
      k_mlred<<<(unsigned)((rows_total + 255) / 256), 256, 0, stream>>>(
          MLbuf, Fqbuf, CH, rows_total);
      int nblk2 = nbc * ntm * (DDIM / 256);
      k_gemm2<<<nblk2, 512, 0, stream>>>(Ubuf, (long)CH * SYY, 0, SYY,
                                         Yt16, (long)DDIM * SYY, SYY,
                                         out + (size_t)b0 * SX * 2 * DDIM,
                                         (long)SX * 2 * DDIM, i0, 2 * DDIM, DDIM,
                                         Fqbuf, CH,
                                         SYY, ntm, DDIM / 256, nblk2);
    }
  }
}

// Round 11
// 220.698 us; speedup vs baseline: 1.1914x; 1.1914x over previous
//
#include <hip/hip_runtime.h>
#include <stdint.h>

#define SX 2048
#define SYY 2048
#define DDIM 1024
#define NBATCH 8

typedef _Float16 f16;
typedef __attribute__((ext_vector_type(2))) _Float16 h2_t;
typedef __attribute__((ext_vector_type(4))) _Float16 h4_t;
typedef __attribute__((ext_vector_type(8))) _Float16 h8_t;
typedef __attribute__((ext_vector_type(4))) float fx4_t;

__device__ __forceinline__ void gload_lds16(const void* g, void* l) {
  __builtin_amdgcn_global_load_lds((const __attribute__((address_space(1))) void*)g,
                                   (__attribute__((address_space(3))) void*)l,
                                   16, 0, 0);
}

// ---- prep: copy x into out[:, :, 0:D] (fp32) AND convert x -> fp16 ----
__global__ __launch_bounds__(256) void k_prep_x(const float4* __restrict__ x,
                                                float* __restrict__ out,
                                                h4_t* __restrict__ x16, long n4) {
  long i = (long)blockIdx.x * blockDim.x + threadIdx.x;
  long stride = (long)gridDim.x * blockDim.x;
  for (; i < n4; i += stride) {
    long bi = i >> 8;            // / (DDIM/4)
    int dq = (int)(i & 255);
    float4 v = x[i];
    *(float4*)(out + bi * (2 * DDIM) + dq * 4) = v;
    h4_t h = { (f16)v.x, (f16)v.y, (f16)v.z, (f16)v.w };
    x16[i] = h;
  }
}

// ---- y[z][j][d] fp32 -> Y16[z][j][d] fp16 and Yt16[z][d][j] fp16 ----
__global__ __launch_bounds__(256) void k_trans(const float* __restrict__ y,
                                               f16* __restrict__ y16,
                                               f16* __restrict__ yt16) {
  __shared__ f16 tile[64][72];
  int z = blockIdx.z;
  int d0 = blockIdx.x * 64, j0 = blockIdx.y * 64;
  const float* yb = y + (size_t)z * SYY * DDIM;
  f16* y16b = y16 + (size_t)z * SYY * DDIM;
  f16* ytb = yt16 + (size_t)z * DDIM * SYY;
  int t = threadIdx.x;
  int jl = t >> 2;
  int dq = t & 3;
#pragma unroll
  for (int s = 0; s < 4; ++s) {
    int dl = dq * 16 + s * 4;
    float4 v = *(const float4*)(yb + (size_t)(j0 + jl) * DDIM + d0 + dl);
    h4_t h = { (f16)v.x, (f16)v.y, (f16)v.z, (f16)v.w };
    *(h4_t*)(y16b + (size_t)(j0 + jl) * DDIM + d0 + dl) = h;
    *(h4_t*)&tile[jl][dl] = h;
  }
  __syncthreads();
  int dl2 = t >> 2;
  int jq = t & 3;
  f16 vbuf[16] __attribute__((aligned(16)));
#pragma unroll
  for (int u = 0; u < 16; ++u) vbuf[u] = tile[jq * 16 + u][dl2];
  f16* orow = ytb + (size_t)(d0 + dl2) * SYY + j0 + jq * 16;
  *(uint4*)orow = *(const uint4*)&vbuf[0];
  *(uint4*)(orow + 8) = *(const uint4*)&vbuf[8];
}

// ==== shared 256x256 8-phase GEMM machinery (round-3 verified ledger) ====
#define PH_BAR() __builtin_amdgcn_s_barrier()

#define STAGE_A(SLOT, HALF, T) {                                               \
    const f16* s_ = aRow + (size_t)((HALF) * 64) * lda + (T) * 64;             \
    f16* d_ = lds + (SLOT) * 8192 + dstoff;                                    \
    gload_lds16(s_, d_);                                                       \
    gload_lds16(s_ + (size_t)128 * lda, d_ + 4096); }

#define STAGE_B(SLOT, HALF, T) {                                               \
    const f16* s_ = bRow + (size_t)((HALF) * 32) * ldb + (T) * 64;             \
    f16* d_ = lds + (SLOT) * 8192 + dstoff;                                    \
    gload_lds16(s_, d_);                                                       \
    gload_lds16(s_ + (size_t)128 * ldb, d_ + 4096); }

#define RD_A(PTR, CB) { _Pragma("unroll") for (int i_ = 0; i_ < 4; ++i_) {     \
    af[i_][0] = *(const h8_t*)((PTR) + (CB) + i_ * 2048 + kb0);                \
    af[i_][1] = *(const h8_t*)((PTR) + (CB) + i_ * 2048 + kb1); } }

// gemm2 variant: scale A-fragments by per-row per-K-tile factor FD[MOFF + i]
#define RD_A_S(PTR, CB, MOFF, FD) { _Pragma("unroll") for (int i_ = 0; i_ < 4; ++i_) { \
    h8_t a0 = *(const h8_t*)((PTR) + (CB) + i_ * 2048 + kb0);                  \
    h8_t a1 = *(const h8_t*)((PTR) + (CB) + i_ * 2048 + kb1);                  \
    h2_t* p0 = (h2_t*)&a0; h2_t* p1 = (h2_t*)&a1;                              \
    _Pragma("unroll") for (int q_ = 0; q_ < 4; ++q_) {                         \
      p0[q_] *= FD[(MOFF) + i_]; p1[q_] *= FD[(MOFF) + i_]; }                  \
    af[i_][0] = a0; af[i_][1] = a1; } }

#define RD_B(PTR, CB, NH) { _Pragma("unroll") for (int j_ = 0; j_ < 2; ++j_) { \
    bf[(NH) + j_][0] = *(const h8_t*)((PTR) + (CB) + j_ * 2048 + kb0);         \
    bf[(NH) + j_][1] = *(const h8_t*)((PTR) + (CB) + j_ * 2048 + kb1); } }

#define MM(MH, NH) { __builtin_amdgcn_s_setprio(1);                            \
  _Pragma("unroll") for (int i_ = 0; i_ < 4; ++i_)                             \
  _Pragma("unroll") for (int j_ = 0; j_ < 2; ++j_) {                           \
    acc[(MH) + i_][(NH) + j_] = __builtin_amdgcn_mfma_f32_16x16x32_f16(        \
        af[i_][0], bf[(NH) + j_][0], acc[(MH) + i_][(NH) + j_], 0, 0, 0);      \
    acc[(MH) + i_][(NH) + j_] = __builtin_amdgcn_mfma_f32_16x16x32_f16(        \
        af[i_][1], bf[(NH) + j_][1], acc[(MH) + i_][(NH) + j_], 0, 0, 0); }    \
  __builtin_amdgcn_s_setprio(0); }

// tile-id decode with XCD chunking + n-major half-m ordering for L2 reuse
#define DECODE_TILE()                                                          \
  int bid = blockIdx.x;                                                        \
  int id = bid;                                                                \
  if ((nblk & 7) == 0) { int cpx = nblk >> 3; id = (bid & 7) * cpx + (bid >> 3); } \
  int tpz = ntm * ntn;                                                         \
  int z = id / tpz;                                                            \
  int rem = id - z * tpz;                                                      \
  int mt, ntl;                                                                 \
  if ((ntm & 1) == 0) {                                                        \
    int ht = tpz >> 1, hm = ntm >> 1;                                          \
    int half = rem / ht, j = rem - half * ht;                                  \
    ntl = j / hm; mt = half * hm + (j - ntl * hm);                             \
  } else { mt = rem / ntn; ntl = rem - mt * ntn; }                             \
  int m0 = mt * 256, n0 = ntl * 256;

#define GEMM_COMMON_SETUP()                                                    \
  const int tid = threadIdx.x;                                                 \
  const int lane = tid & 63, w = tid >> 6;                                     \
  const int wr = w >> 2, wc = w & 3;                                           \
  const int fr = lane & 15, fh = lane >> 4;                                    \
  const f16* Ab = A + (size_t)z * a_zs + (size_t)(a_row0 + m0) * lda;          \
  const f16* Bb = B + (size_t)z * b_zs + (size_t)n0 * ldb;                     \
  const int l0 = 8 * w + (lane >> 3);                                          \
  const int r0a = l0;                                                          \
  const int r0b = ((l0 >> 5) << 6) | (l0 & 31);                                \
  const int swz = 8 * ((lane & 7) ^ (lane >> 3));                              \
  const f16* aRow = Ab + (size_t)r0a * lda + swz;                              \
  const f16* bRow = Bb + (size_t)r0b * ldb + swz;                              \
  const int dstoff = w * 512 + lane * 8;                                       \
  const char* ldsAlo = (const char*)lds + wr * 8192 + fr * 128;                \
  const char* ldsAhi = ldsAlo + 16384;                                         \
  const char* ldsBlo = (const char*)lds + 32768 + wc * 4096 + fr * 128;        \
  const char* ldsBhi = ldsBlo + 16384;                                         \
  const int kb0 = ((0 + fh) ^ (fr & 7)) * 16;                                  \
  const int kb1 = ((4 + fh) ^ (fr & 7)) * 16;

// ==== GEMM1: S = X16 . Y16^T, barrier-free per-wave softmax epilogue ====
// u = exp(s - m_quarter) per 64-col quarter; (m,l) emitted per (row,tile,wc).
__global__ __launch_bounds__(512, 2) void k_gemm1(
    const f16* __restrict__ A, long a_zs, int a_row0, int lda,
    const f16* __restrict__ B, long b_zs, int ldb,
    f16* __restrict__ U, long u_zs,
    float2* __restrict__ ML, int mrows,
    int K, int ntm, int ntn, int nblk)
{
  __shared__ f16 lds[65536];
  DECODE_TILE();
  GEMM_COMMON_SETUP();

  const int nt = K >> 6;
  const int ng = nt >> 1;

  fx4_t acc[8][4];
#pragma unroll
  for (int i = 0; i < 8; ++i)
#pragma unroll
    for (int j = 0; j < 4; ++j) { fx4_t zv = {0.f,0.f,0.f,0.f}; acc[i][j] = zv; }
  h8_t af[4][2], bf[4][2];

  STAGE_A(0, 0, 0); STAGE_A(1, 1, 0); STAGE_B(2, 0, 0); STAGE_B(3, 1, 0);
  STAGE_A(4, 0, 1); STAGE_B(6, 0, 1); STAGE_B(7, 1, 1);
  asm volatile("s_waitcnt vmcnt(6)" ::: "memory");
  PH_BAR();

  for (int g = 0; g < ng; ++g) {
    const int T1 = 2 * g + 1, T2 = 2 * g + 2, T3 = 2 * g + 3;
    const bool nl = (g < ng - 1);
    RD_A(ldsAlo, 0); RD_B(ldsBlo, 0, 0);
    STAGE_A(5, 1, T1);
    PH_BAR();
    MM(0, 0);
    PH_BAR();
    RD_B(ldsBhi, 0, 2);
    if (nl) STAGE_A(0, 0, T2);
    PH_BAR();
    MM(0, 2);
    PH_BAR();
    RD_A(ldsAhi, 0);
    if (nl) STAGE_B(2, 0, T2);
    PH_BAR();
    MM(4, 0);
    PH_BAR();
    if (nl) STAGE_B(3, 1, T2);
    PH_BAR();
    MM(4, 2);
    if (nl) { asm volatile("s_waitcnt vmcnt(6)" ::: "memory"); }
    else    { asm volatile("s_waitcnt vmcnt(0)" ::: "memory"); }
    PH_BAR();
    RD_A(ldsAlo, 65536); RD_B(ldsBlo, 65536, 0);
    if (nl) STAGE_A(1, 1, T2);
    PH_BAR();
    MM(0, 0);
    PH_BAR();
    RD_B(ldsBhi, 65536, 2);
    if (nl) STAGE_A(4, 0, T3);
    PH_BAR();
    MM(0, 2);
    PH_BAR();
    RD_A(ldsAhi, 65536);
    if (nl) STAGE_B(6, 0, T3);
    PH_BAR();
    MM(4, 0);
    PH_BAR();
    if (nl) STAGE_B(7, 1, T3);
    PH_BAR();
    MM(4, 2);
    asm volatile("s_waitcnt vmcnt(6)" ::: "memory");
    PH_BAR();
  }

  // ---- barrier-free per-wave epilogue: quarter softmax + scalar U stores ----
  const int rbase = wr * 128 + fh * 4;
  f16* Ub = U + (size_t)z * u_zs;
  // ML layout: [z][ntl(8)][wc(4)][mrows]
  float2* MLp = ML + (((size_t)z * 8 + (n0 >> 8)) * 4 + wc) * mrows + m0;
#pragma unroll
  for (int mi = 0; mi < 8; ++mi)
#pragma unroll
    for (int rr = 0; rr < 4; ++rr) {
      float am = fmaxf(fmaxf(acc[mi][0][rr], acc[mi][1][rr]),
                       fmaxf(acc[mi][2][rr], acc[mi][3][rr]));
      am = fmaxf(am, __shfl_xor(am, 1)); am = fmaxf(am, __shfl_xor(am, 2));
      am = fmaxf(am, __shfl_xor(am, 4)); am = fmaxf(am, __shfl_xor(am, 8));
      float s = 0.f;
#pragma unroll
      for (int ni = 0; ni < 4; ++ni) {
        float e = __expf(acc[mi][ni][rr] - am);
        acc[mi][ni][rr] = e; s += e;
      }
      s += __shfl_xor(s, 1); s += __shfl_xor(s, 2);
      s += __shfl_xor(s, 4); s += __shfl_xor(s, 8);
      int row = rbase + mi * 16 + rr;
      if (fr == 0) { float2 v; v.x = am; v.y = s; MLp[row] = v; }
#pragma unroll
      for (int ni = 0; ni < 4; ++ni)
        Ub[(size_t)(m0 + row) * SYY + n0 + wc * 64 + ni * 16 + fr] =
            (f16)acc[mi][ni][rr];
    }
}

// ---- per-row combine: 32 quarter (m,l) -> factor per 64-col block (f16),
//      written THREAD-PACKED for gemm2: [z][t][mt*256 + wr*128 + fr*8 + i]
__global__ __launch_bounds__(256) void k_mlred(const float2* __restrict__ ML,
                                               f16* __restrict__ Fq,
                                               int rows, long total) {
  long idx = (long)blockIdx.x * blockDim.x + threadIdx.x;
  if (idx >= total) return;
  int z = (int)(idx / rows);
  int r = (int)(idx - (long)z * rows);
  float M = -3.4e38f;
  float2 v[32];
#pragma unroll
  for (int t = 0; t < 32; ++t) {
    v[t] = ML[((size_t)z * 32 + t) * rows + r];
    M = fmaxf(M, v[t].x);
  }
  float L = 0.f;
#pragma unroll
  for (int t = 0; t < 32; ++t) L += v[t].y * __expf(v[t].x - M);
  float inv = 1.0f / L;
  // packed position for row r = mt*256 + wr*128 + i*16 + fr
  int mt = r >> 8, rem = r & 255;
  int wr2 = rem >> 7, rm2 = rem & 127;
  int ii = rm2 >> 4, fr2 = rm2 & 15;
  int pk = mt * 256 + wr2 * 128 + fr2 * 8 + ii;
#pragma unroll
  for (int t = 0; t < 32; ++t)
    Fq[((size_t)z * 32 + t) * rows + pk] = (f16)(__expf(v[t].x - M) * inv);
}

// ==== GEMM2: out_right = (u * factor) . Yt^T, per-K-tile h8-packed factors ====
__global__ __launch_bounds__(512, 2) void k_gemm2(
    const f16* __restrict__ A, long a_zs, int a_row0, int lda,
    const f16* __restrict__ B, long b_zs, int ldb,
    float* __restrict__ C, long c_zs, int c_row0, int ldc, int c_col0,
    const f16* __restrict__ Fq, int mrows,
    int K, int ntm, int ntn, int nblk)
{
  __shared__ f16 lds[65536];
  DECODE_TILE();
  GEMM_COMMON_SETUP();

  const int nt = K >> 6;
  const int ng = nt >> 1;

  fx4_t acc[8][4];
#pragma unroll
  for (int i = 0; i < 8; ++i)
#pragma unroll
    for (int j = 0; j < 4; ++j) { fx4_t zv = {0.f,0.f,0.f,0.f}; acc[i][j] = zv; }
  h8_t af[4][2], bf[4][2];

  // packed factor base: one h8 load per K-tile table
  const f16* Fb2 = Fq + (size_t)z * 32 * mrows + m0 + wr * 128 + fr * 8;
  h8_t fA8 = *(const h8_t*)(Fb2);                    // table 0
  h8_t fB8 = *(const h8_t*)(Fb2 + mrows);            // table 1

  STAGE_A(0, 0, 0); STAGE_A(1, 1, 0); STAGE_B(2, 0, 0); STAGE_B(3, 1, 0);
  STAGE_A(4, 0, 1); STAGE_B(6, 0, 1); STAGE_B(7, 1, 1);
  asm volatile("s_waitcnt vmcnt(6)" ::: "memory");   // drains fA8,fB8 + tile0
  PH_BAR();

  for (int g = 0; g < ng; ++g) {
    const int T1 = 2 * g + 1, T2 = 2 * g + 2, T3 = 2 * g + 3;
    const bool nl = (g < ng - 1);
    // unpack current tables (fA8/fB8 drained by prologue / prev ph7 vmcnt)
    h2_t fcA[8], fcB[8];
#pragma unroll
    for (int i = 0; i < 8; ++i) {
      f16 a = fA8[i], b = fB8[i];
      h2_t da; da[0] = a; da[1] = a; fcA[i] = da;
      h2_t db; db[0] = b; db[1] = b; fcB[i] = db;
    }
    RD_A_S(ldsAlo, 0, 0, fcA); RD_B(ldsBlo, 0, 0);
    STAGE_A(5, 1, T1);
    PH_BAR(); MM(0, 0); PH_BAR();
    RD_B(ldsBhi, 0, 2);
    if (nl) STAGE_A(0, 0, T2);
    PH_BAR(); MM(0, 2); PH_BAR();
    RD_A_S(ldsAhi, 0, 4, fcA);
    if (nl) STAGE_B(2, 0, T2);
    PH_BAR(); MM(4, 0); PH_BAR();
    if (nl) STAGE_B(3, 1, T2);
    PH_BAR(); MM(4, 2);
    if (nl) { asm volatile("s_waitcnt vmcnt(6)" ::: "memory"); }
    else    { asm volatile("s_waitcnt vmcnt(0)" ::: "memory"); }
    PH_BAR();
    // ph4: next-group packed factor loads (2 coalesced h8) after checkpoint;
    // ph7's vmcnt(6) = ph5/6/7 stages exactly -> drains these two loads.
    RD_A_S(ldsAlo, 65536, 0, fcB); RD_B(ldsBlo, 65536, 0);
    if (nl) {
      fA8 = *(const h8_t*)(Fb2 + (size_t)(2 * g + 2) * mrows);
      fB8 = *(const h8_t*)(Fb2 + (size_t)(2 * g + 3) * mrows);
    }
    if (nl) STAGE_A(1, 1, T2);
    PH_BAR(); MM(0, 0); PH_BAR();
    RD_B(ldsBhi, 65536, 2);
    if (nl) STAGE_A(4, 0, T3);
    PH_BAR(); MM(0, 2); PH_BAR();
    RD_A_S(ldsAhi, 65536, 4, fcB);
    if (nl) STAGE_B(6, 0, T3);
    PH_BAR(); MM(4, 0); PH_BAR();
    if (nl) STAGE_B(7, 1, T3);
    PH_BAR(); MM(4, 2);
    asm volatile("s_waitcnt vmcnt(6)" ::: "memory");
    PH_BAR();
  }

  float* Cb = C + (size_t)z * c_zs +
              (size_t)(c_row0 + m0 + wr * 128) * ldc + c_col0 + n0 + wc * 64;
#pragma unroll
  for (int mi = 0; mi < 8; ++mi)
#pragma unroll
    for (int ni = 0; ni < 4; ++ni)
#pragma unroll
      for (int r = 0; r < 4; ++r)
        Cb[(size_t)(mi * 16 + fh * 4 + r) * ldc + ni * 16 + fr] = acc[mi][ni][r];
}

extern "C" void kernel_launch(void* const* d_in, const int* in_sizes, int n_in,
                              void* d_out, int out_size, void* d_ws, size_t ws_size,
                              hipStream_t stream) {
  (void)in_sizes; (void)n_in; (void)out_size;
  const float* x = (const float*)d_in[0];
  const float* y = (const float*)d_in[1];
  float* out = (float*)d_out;

  // ws per group: U(f16) | ML(float2 x32) | Fq(f16 x32) | X16 | Y16 | Yt16
  size_t per_batch = (size_t)SX * SYY * 2 + (size_t)32 * SX * 8 + (size_t)32 * SX * 2 +
                     (size_t)SX * DDIM * 2 + (size_t)SYY * DDIM * 2 +
                     (size_t)DDIM * SYY * 2;
  int nb = (int)(ws_size / per_batch);
  if (nb > NBATCH) nb = NBATCH;
  int CH = SX;
  if (nb < 1) {
    nb = 1;
    size_t conv = (size_t)SX * DDIM * 2 + (size_t)SYY * DDIM * 2 +
                  (size_t)DDIM * SYY * 2;
    size_t avail = ws_size > conv ? ws_size - conv : 0;
    long ch = (long)(avail / ((size_t)SYY * 2 + 320));
    ch = (ch / 256) * 256;
    if (ch < 256) ch = 256;
    if (ch > SX) ch = SX;
    CH = (int)ch;
  }

  char* w = (char*)d_ws;
  f16* Ubuf = (f16*)w;            size_t off = (size_t)nb * CH * SYY * 2;
  float2* MLbuf = (float2*)(w + off); off += (size_t)nb * 32 * CH * 8;
  f16* Fqbuf = (f16*)(w + off);   off += (size_t)nb * 32 * CH * 2;
  f16* X16 = (f16*)(w + off);     off += (size_t)nb * SX * DDIM * 2;
  f16* Y16 = (f16*)(w + off);     off += (size_t)nb * SYY * DDIM * 2;
  f16* Yt16 = (f16*)(w + off);

  for (int b0 = 0; b0 < NBATCH; b0 += nb) {
    int nbc = (NBATCH - b0 < nb) ? (NBATCH - b0) : nb;
    k_prep_x<<<2048, 256, 0, stream>>>(
        (const float4*)(x + (size_t)b0 * SX * DDIM),
        out + (size_t)b0 * SX * 2 * DDIM, (h4_t*)X16,
        (long)nbc * SX * (DDIM / 4));
    dim3 tg(DDIM / 64, SYY / 64, nbc);
    k_trans<<<tg, 256, 0, stream>>>(y + (size_t)b0 * SYY * DDIM, Y16, Yt16);

    for (int i0 = 0; i0 < SX; i0 += CH) {
      int ntm = CH / 256;
      int nblk1 = nbc * ntm * (SYY / 256);
      k_gemm1<<<nblk1, 512, 0, stream>>>(X16, (long)SX * DDIM, i0, DDIM,
                                         Y16, (long)SYY * DDIM, DDIM,
                                         Ubuf, (long)CH * SYY,
                                         MLbuf, CH,
                                         DDIM, ntm, SYY / 256, nblk1);
      long rows_total = (long)nbc * CH;
      k_mlred<<<(unsigned)((rows_total + 255) / 256), 256, 0, stream>>>(
          MLbuf, Fqbuf, CH, rows_total);
      int nblk2 = nbc * ntm * (DDIM / 256);
      k_gemm2<<<nblk2, 512, 0, stream>>>(Ubuf, (long)CH * SYY, 0, SYY,
                                         Yt16, (long)DDIM * SYY, SYY,
                                         out + (size_t)b0 * SX * 2 * DDIM,
                                         (long)SX * 2 * DDIM, i0, 2 * DDIM, DDIM,
                                         Fqbuf, CH,
                                         SYY, ntm, DDIM / 256, nblk2);
    }
  }
}

// Round 13
// 214.202 us; speedup vs baseline: 1.2275x; 1.0303x over previous
//
#include <hip/hip_runtime.h>
#include <stdint.h>

#define SX 2048
#define SYY 2048
#define DDIM 1024
#define NBATCH 8

typedef _Float16 f16;
typedef __attribute__((ext_vector_type(2))) _Float16 h2_t;
typedef __attribute__((ext_vector_type(4))) _Float16 h4_t;
typedef __attribute__((ext_vector_type(8))) _Float16 h8_t;
typedef __attribute__((ext_vector_type(4))) float fx4_t;

__device__ __forceinline__ void gload_lds16(const void* g, void* l) {
  __builtin_amdgcn_global_load_lds((const __attribute__((address_space(1))) void*)g,
                                   (__attribute__((address_space(3))) void*)l,
                                   16, 0, 0);
}

// DPP lane-permute within 16-lane rows (VALU pipe — avoids ds_bpermute).
// ctrl must be a compile-time constant -> template parameter.
template <int CTRL>
__device__ __forceinline__ float dpp_mov(float v) {
  return __int_as_float(__builtin_amdgcn_update_dpp(
      0, __float_as_int(v), CTRL, 0xf, 0xf, true));
}
// 16-lane reduction: quad_perm xor1 (0xB1), xor2 (0x4E), row_ror:4, row_ror:8
#define RED16_MAX(V) { V = fmaxf(V, dpp_mov<0xB1>(V));                         \
                       V = fmaxf(V, dpp_mov<0x4E>(V));                         \
                       V = fmaxf(V, dpp_mov<0x124>(V));                        \
                       V = fmaxf(V, dpp_mov<0x128>(V)); }
#define RED16_SUM(V) { V += dpp_mov<0xB1>(V); V += dpp_mov<0x4E>(V);           \
                       V += dpp_mov<0x124>(V); V += dpp_mov<0x128>(V); }

// ---- prep: copy x into out[:, :, 0:D] (fp32) AND convert x -> fp16 ----
__global__ __launch_bounds__(256) void k_prep_x(const float4* __restrict__ x,
                                                float* __restrict__ out,
                                                h4_t* __restrict__ x16, long n4) {
  long i = (long)blockIdx.x * blockDim.x + threadIdx.x;
  long stride = (long)gridDim.x * blockDim.x;
  for (; i < n4; i += stride) {
    long bi = i >> 8;            // / (DDIM/4)
    int dq = (int)(i & 255);
    float4 v = x[i];
    *(float4*)(out + bi * (2 * DDIM) + dq * 4) = v;
    h4_t h = { (f16)v.x, (f16)v.y, (f16)v.z, (f16)v.w };
    x16[i] = h;
  }
}

// ---- y[z][j][d] fp32 -> Y16[z][j][d] fp16 and Yt16[z][d][j] fp16 ----
__global__ __launch_bounds__(256) void k_trans(const float* __restrict__ y,
                                               f16* __restrict__ y16,
                                               f16* __restrict__ yt16) {
  __shared__ f16 tile[64][72];
  int z = blockIdx.z;
  int d0 = blockIdx.x * 64, j0 = blockIdx.y * 64;
  const float* yb = y + (size_t)z * SYY * DDIM;
  f16* y16b = y16 + (size_t)z * SYY * DDIM;
  f16* ytb = yt16 + (size_t)z * DDIM * SYY;
  int t = threadIdx.x;
  int jl = t >> 2;
  int dq = t & 3;
#pragma unroll
  for (int s = 0; s < 4; ++s) {
    int dl = dq * 16 + s * 4;
    float4 v = *(const float4*)(yb + (size_t)(j0 + jl) * DDIM + d0 + dl);
    h4_t h = { (f16)v.x, (f16)v.y, (f16)v.z, (f16)v.w };
    *(h4_t*)(y16b + (size_t)(j0 + jl) * DDIM + d0 + dl) = h;
    *(h4_t*)&tile[jl][dl] = h;
  }
  __syncthreads();
  int dl2 = t >> 2;
  int jq = t & 3;
  f16 vbuf[16] __attribute__((aligned(16)));
#pragma unroll
  for (int u = 0; u < 16; ++u) vbuf[u] = tile[jq * 16 + u][dl2];
  f16* orow = ytb + (size_t)(d0 + dl2) * SYY + j0 + jq * 16;
  *(uint4*)orow = *(const uint4*)&vbuf[0];
  *(uint4*)(orow + 8) = *(const uint4*)&vbuf[8];
}

// ==== shared 256x256 8-phase GEMM machinery (round-3 verified ledger) ====
#define PH_BAR() __builtin_amdgcn_s_barrier()

#define STAGE_A(SLOT, HALF, T) {                                               \
    const f16* s_ = aRow + (size_t)((HALF) * 64) * lda + (T) * 64;             \
    f16* d_ = lds + (SLOT) * 8192 + dstoff;                                    \
    gload_lds16(s_, d_);                                                       \
    gload_lds16(s_ + (size_t)128 * lda, d_ + 4096); }

#define STAGE_B(SLOT, HALF, T) {                                               \
    const f16* s_ = bRow + (size_t)((HALF) * 32) * ldb + (T) * 64;             \
    f16* d_ = lds + (SLOT) * 8192 + dstoff;                                    \
    gload_lds16(s_, d_);                                                       \
    gload_lds16(s_ + (size_t)128 * ldb, d_ + 4096); }

#define RD_A(PTR, CB) { _Pragma("unroll") for (int i_ = 0; i_ < 4; ++i_) {     \
    af[i_][0] = *(const h8_t*)((PTR) + (CB) + i_ * 2048 + kb0);                \
    af[i_][1] = *(const h8_t*)((PTR) + (CB) + i_ * 2048 + kb1); } }

// gemm2 variant: scale A-fragments by per-row per-K-tile factor FD[MOFF + i]
#define RD_A_S(PTR, CB, MOFF, FD) { _Pragma("unroll") for (int i_ = 0; i_ < 4; ++i_) { \
    h8_t a0 = *(const h8_t*)((PTR) + (CB) + i_ * 2048 + kb0);                  \
    h8_t a1 = *(const h8_t*)((PTR) + (CB) + i_ * 2048 + kb1);                  \
    h2_t* p0 = (h2_t*)&a0; h2_t* p1 = (h2_t*)&a1;                              \
    _Pragma("unroll") for (int q_ = 0; q_ < 4; ++q_) {                         \
      p0[q_] *= FD[(MOFF) + i_]; p1[q_] *= FD[(MOFF) + i_]; }                  \
    af[i_][0] = a0; af[i_][1] = a1; } }

#define RD_B(PTR, CB, NH) { _Pragma("unroll") for (int j_ = 0; j_ < 2; ++j_) { \
    bf[(NH) + j_][0] = *(const h8_t*)((PTR) + (CB) + j_ * 2048 + kb0);         \
    bf[(NH) + j_][1] = *(const h8_t*)((PTR) + (CB) + j_ * 2048 + kb1); } }

#define MM(MH, NH) { __builtin_amdgcn_s_setprio(1);                            \
  _Pragma("unroll") for (int i_ = 0; i_ < 4; ++i_)                             \
  _Pragma("unroll") for (int j_ = 0; j_ < 2; ++j_) {                           \
    acc[(MH) + i_][(NH) + j_] = __builtin_amdgcn_mfma_f32_16x16x32_f16(        \
        af[i_][0], bf[(NH) + j_][0], acc[(MH) + i_][(NH) + j_], 0, 0, 0);      \
    acc[(MH) + i_][(NH) + j_] = __builtin_amdgcn_mfma_f32_16x16x32_f16(        \
        af[i_][1], bf[(NH) + j_][1], acc[(MH) + i_][(NH) + j_], 0, 0, 0); }    \
  __builtin_amdgcn_s_setprio(0); }

// tile-id decode with XCD chunking + n-major half-m ordering for L2 reuse
#define DECODE_TILE()                                                          \
  int bid = blockIdx.x;                                                        \
  int id = bid;                                                                \
  if ((nblk & 7) == 0) { int cpx = nblk >> 3; id = (bid & 7) * cpx + (bid >> 3); } \
  int tpz = ntm * ntn;                                                         \
  int z = id / tpz;                                                            \
  int rem = id - z * tpz;                                                      \
  int mt, ntl;                                                                 \
  if ((ntm & 1) == 0) {                                                        \
    int ht = tpz >> 1, hm = ntm >> 1;                                          \
    int half = rem / ht, j = rem - half * ht;                                  \
    ntl = j / hm; mt = half * hm + (j - ntl * hm);                             \
  } else { mt = rem / ntn; ntl = rem - mt * ntn; }                             \
  int m0 = mt * 256, n0 = ntl * 256;

#define GEMM_COMMON_SETUP()                                                    \
  const int tid = threadIdx.x;                                                 \
  const int lane = tid & 63, w = tid >> 6;                                     \
  const int wr = w >> 2, wc = w & 3;                                           \
  const int fr = lane & 15, fh = lane >> 4;                                    \
  const f16* Ab = A + (size_t)z * a_zs + (size_t)(a_row0 + m0) * lda;          \
  const f16* Bb = B + (size_t)z * b_zs + (size_t)n0 * ldb;                     \
  const int l0 = 8 * w + (lane >> 3);                                          \
  const int r0a = l0;                                                          \
  const int r0b = ((l0 >> 5) << 6) | (l0 & 31);                                \
  const int swz = 8 * ((lane & 7) ^ (lane >> 3));                              \
  const f16* aRow = Ab + (size_t)r0a * lda + swz;                              \
  const f16* bRow = Bb + (size_t)r0b * ldb + swz;                              \
  const int dstoff = w * 512 + lane * 8;                                       \
  const char* ldsAlo = (const char*)lds + wr * 8192 + fr * 128;                \
  const char* ldsAhi = ldsAlo + 16384;                                         \
  const char* ldsBlo = (const char*)lds + 32768 + wc * 4096 + fr * 128;        \
  const char* ldsBhi = ldsBlo + 16384;                                         \
  const int kb0 = ((0 + fh) ^ (fr & 7)) * 16;                                  \
  const int kb1 = ((4 + fh) ^ (fr & 7)) * 16;

// ==== GEMM1: S = X16 . Y16^T, barrier-free per-wave softmax epilogue ====
// u = exp(s - m_quarter) per 64-col quarter; (m,l) emitted per (row,tile,wc).
__global__ __launch_bounds__(512, 2) void k_gemm1(
    const f16* __restrict__ A, long a_zs, int a_row0, int lda,
    const f16* __restrict__ B, long b_zs, int ldb,
    f16* __restrict__ U, long u_zs,
    float2* __restrict__ ML, int mrows,
    int K, int ntm, int ntn, int nblk)
{
  __shared__ f16 lds[65536];
  DECODE_TILE();
  GEMM_COMMON_SETUP();

  const int nt = K >> 6;
  const int ng = nt >> 1;

  fx4_t acc[8][4];
#pragma unroll
  for (int i = 0; i < 8; ++i)
#pragma unroll
    for (int j = 0; j < 4; ++j) { fx4_t zv = {0.f,0.f,0.f,0.f}; acc[i][j] = zv; }
  h8_t af[4][2], bf[4][2];

  STAGE_A(0, 0, 0); STAGE_A(1, 1, 0); STAGE_B(2, 0, 0); STAGE_B(3, 1, 0);
  STAGE_A(4, 0, 1); STAGE_B(6, 0, 1); STAGE_B(7, 1, 1);
  asm volatile("s_waitcnt vmcnt(6)" ::: "memory");
  PH_BAR();

  for (int g = 0; g < ng; ++g) {
    const int T1 = 2 * g + 1, T2 = 2 * g + 2, T3 = 2 * g + 3;
    const bool nl = (g < ng - 1);
    RD_A(ldsAlo, 0); RD_B(ldsBlo, 0, 0);
    STAGE_A(5, 1, T1);
    PH_BAR();
    MM(0, 0);
    PH_BAR();
    RD_B(ldsBhi, 0, 2);
    if (nl) STAGE_A(0, 0, T2);
    PH_BAR();
    MM(0, 2);
    PH_BAR();
    RD_A(ldsAhi, 0);
    if (nl) STAGE_B(2, 0, T2);
    PH_BAR();
    MM(4, 0);
    PH_BAR();
    if (nl) STAGE_B(3, 1, T2);
    PH_BAR();
    MM(4, 2);
    if (nl) { asm volatile("s_waitcnt vmcnt(6)" ::: "memory"); }
    else    { asm volatile("s_waitcnt vmcnt(0)" ::: "memory"); }
    PH_BAR();
    RD_A(ldsAlo, 65536); RD_B(ldsBlo, 65536, 0);
    if (nl) STAGE_A(1, 1, T2);
    PH_BAR();
    MM(0, 0);
    PH_BAR();
    RD_B(ldsBhi, 65536, 2);
    if (nl) STAGE_A(4, 0, T3);
    PH_BAR();
    MM(0, 2);
    PH_BAR();
    RD_A(ldsAhi, 65536);
    if (nl) STAGE_B(6, 0, T3);
    PH_BAR();
    MM(4, 0);
    PH_BAR();
    if (nl) STAGE_B(7, 1, T3);
    PH_BAR();
    MM(4, 2);
    asm volatile("s_waitcnt vmcnt(6)" ::: "memory");
    PH_BAR();
  }

  // ---- barrier-free per-wave epilogue: DPP quarter softmax + U stores ----
  const int rbase = wr * 128 + fh * 4;
  f16* Ub = U + (size_t)z * u_zs;
  // ML layout: [z][ntl(8)][wc(4)][mrows]
  float2* MLp = ML + (((size_t)z * 8 + (n0 >> 8)) * 4 + wc) * mrows + m0;
#pragma unroll
  for (int mi = 0; mi < 8; ++mi)
#pragma unroll
    for (int rr = 0; rr < 4; ++rr) {
      float am = fmaxf(fmaxf(acc[mi][0][rr], acc[mi][1][rr]),
                       fmaxf(acc[mi][2][rr], acc[mi][3][rr]));
      RED16_MAX(am);
      float s = 0.f;
#pragma unroll
      for (int ni = 0; ni < 4; ++ni) {
        float e = __expf(acc[mi][ni][rr] - am);
        acc[mi][ni][rr] = e; s += e;
      }
      RED16_SUM(s);
      int row = rbase + mi * 16 + rr;
      if (fr == 0) { float2 v; v.x = am; v.y = s; MLp[row] = v; }
#pragma unroll
      for (int ni = 0; ni < 4; ++ni)
        Ub[(size_t)(m0 + row) * SYY + n0 + wc * 64 + ni * 16 + fr] =
            (f16)acc[mi][ni][rr];
    }
}

// ---- per-row combine: 32 quarter (m,l) -> factor per 64-col block (f16),
//      written THREAD-PACKED for gemm2: [z][t][mt*256 + wr*128 + fr*8 + i]
__global__ __launch_bounds__(256) void k_mlred(const float2* __restrict__ ML,
                                               f16* __restrict__ Fq,
                                               int rows, long total) {
  long idx = (long)blockIdx.x * blockDim.x + threadIdx.x;
  if (idx >= total) return;
  int z = (int)(idx / rows);
  int r = (int)(idx - (long)z * rows);
  float M = -3.4e38f;
  float2 v[32];
#pragma unroll
  for (int t = 0; t < 32; ++t) {
    v[t] = ML[((size_t)z * 32 + t) * rows + r];
    M = fmaxf(M, v[t].x);
  }
  float L = 0.f;
#pragma unroll
  for (int t = 0; t < 32; ++t) L += v[t].y * __expf(v[t].x - M);
  float inv = 1.0f / L;
  // packed position for row r = mt*256 + wr*128 + i*16 + fr
  int mt = r >> 8, rem = r & 255;
  int wr2 = rem >> 7, rm2 = rem & 127;
  int ii = rm2 >> 4, fr2 = rm2 & 15;
  int pk = mt * 256 + wr2 * 128 + fr2 * 8 + ii;
#pragma unroll
  for (int t = 0; t < 32; ++t)
    Fq[((size_t)z * 32 + t) * rows + pk] = (f16)(__expf(v[t].x - M) * inv);
}

// ==== GEMM2: out_right = (u * factor) . Yt^T, per-K-tile h8-packed factors ====
__global__ __launch_bounds__(512, 2) void k_gemm2(
    const f16* __restrict__ A, long a_zs, int a_row0, int lda,
    const f16* __restrict__ B, long b_zs, int ldb,
    float* __restrict__ C, long c_zs, int c_row0, int ldc, int c_col0,
    const f16* __restrict__ Fq, int mrows,
    int K, int ntm, int ntn, int nblk)
{
  __shared__ f16 lds[65536];
  DECODE_TILE();
  GEMM_COMMON_SETUP();

  const int nt = K >> 6;
  const int ng = nt >> 1;

  fx4_t acc[8][4];
#pragma unroll
  for (int i = 0; i < 8; ++i)
#pragma unroll
    for (int j = 0; j < 4; ++j) { fx4_t zv = {0.f,0.f,0.f,0.f}; acc[i][j] = zv; }
  h8_t af[4][2], bf[4][2];

  // packed factor base: one h8 load per K-tile table
  const f16* Fb2 = Fq + (size_t)z * 32 * mrows + m0 + wr * 128 + fr * 8;
  h8_t fA8 = *(const h8_t*)(Fb2);                    // table 0
  h8_t fB8 = *(const h8_t*)(Fb2 + mrows);            // table 1

  STAGE_A(0, 0, 0); STAGE_A(1, 1, 0); STAGE_B(2, 0, 0); STAGE_B(3, 1, 0);
  STAGE_A(4, 0, 1); STAGE_B(6, 0, 1); STAGE_B(7, 1, 1);
  asm volatile("s_waitcnt vmcnt(6)" ::: "memory");   // drains fA8,fB8 + tile0
  PH_BAR();

  for (int g = 0; g < ng; ++g) {
    const int T1 = 2 * g + 1, T2 = 2 * g + 2, T3 = 2 * g + 3;
    const bool nl = (g < ng - 1);
    // unpack current tables (fA8/fB8 drained by prologue / prev ph7 vmcnt)
    h2_t fcA[8], fcB[8];
#pragma unroll
    for (int i = 0; i < 8; ++i) {
      f16 a = fA8[i], b = fB8[i];
      h2_t da; da[0] = a; da[1] = a; fcA[i] = da;
      h2_t db; db[0] = b; db[1] = b; fcB[i] = db;
    }
    RD_A_S(ldsAlo, 0, 0, fcA); RD_B(ldsBlo, 0, 0);
    STAGE_A(5, 1, T1);
    PH_BAR(); MM(0, 0); PH_BAR();
    RD_B(ldsBhi, 0, 2);
    if (nl) STAGE_A(0, 0, T2);
    PH_BAR(); MM(0, 2); PH_BAR();
    RD_A_S(ldsAhi, 0, 4, fcA);
    if (nl) STAGE_B(2, 0, T2);
    PH_BAR(); MM(4, 0); PH_BAR();
    if (nl) STAGE_B(3, 1, T2);
    PH_BAR(); MM(4, 2);
    if (nl) { asm volatile("s_waitcnt vmcnt(6)" ::: "memory"); }
    else    { asm volatile("s_waitcnt vmcnt(0)" ::: "memory"); }
    PH_BAR();
    // ph4: next-group packed factor loads (2 coalesced h8) after checkpoint;
    // ph7's vmcnt(6) = ph5/6/7 stages exactly -> drains these two loads.
    RD_A_S(ldsAlo, 65536, 0, fcB); RD_B(ldsBlo, 65536, 0);
    if (nl) {
      fA8 = *(const h8_t*)(Fb2 + (size_t)(2 * g + 2) * mrows);
      fB8 = *(const h8_t*)(Fb2 + (size_t)(2 * g + 3) * mrows);
    }
    if (nl) STAGE_A(1, 1, T2);
    PH_BAR(); MM(0, 0); PH_BAR();
    RD_B(ldsBhi, 65536, 2);
    if (nl) STAGE_A(4, 0, T3);
    PH_BAR(); MM(0, 2); PH_BAR();
    RD_A_S(ldsAhi, 65536, 4, fcB);
    if (nl) STAGE_B(6, 0, T3);
    PH_BAR(); MM(4, 0); PH_BAR();
    if (nl) STAGE_B(7, 1, T3);
    PH_BAR(); MM(4, 2);
    asm volatile("s_waitcnt vmcnt(6)" ::: "memory");
    PH_BAR();
  }

  float* Cb = C + (size_t)z * c_zs +
              (size_t)(c_row0 + m0 + wr * 128) * ldc + c_col0 + n0 + wc * 64;
#pragma unroll
  for (int mi = 0; mi < 8; ++mi)
#pragma unroll
    for (int ni = 0; ni < 4; ++ni)
#pragma unroll
      for (int r = 0; r < 4; ++r)
        Cb[(size_t)(mi * 16 + fh * 4 + r) * ldc + ni * 16 + fr] = acc[mi][ni][r];
}

extern "C" void kernel_launch(void* const* d_in, const int* in_sizes, int n_in,
                              void* d_out, int out_size, void* d_ws, size_t ws_size,
                              hipStream_t stream) {
  (void)in_sizes; (void)n_in; (void)out_size;
  const float* x = (const float*)d_in[0];
  const float* y = (const float*)d_in[1];
  float* out = (float*)d_out;

  // ws per group: U(f16) | ML(float2 x32) | Fq(f16 x32) | X16 | Y16 | Yt16
  size_t per_batch = (size_t)SX * SYY * 2 + (size_t)32 * SX * 8 + (size_t)32 * SX * 2 +
                     (size_t)SX * DDIM * 2 + (size_t)SYY * DDIM * 2 +
                     (size_t)DDIM * SYY * 2;
  int nb = (int)(ws_size / per_batch);
  if (nb > NBATCH) nb = NBATCH;
  int CH = SX;
  if (nb < 1) {
    nb = 1;
    size_t conv = (size_t)SX * DDIM * 2 + (size_t)SYY * DDIM * 2 +
                  (size_t)DDIM * SYY * 2;
    size_t avail = ws_size > conv ? ws_size - conv : 0;
    long ch = (long)(avail / ((size_t)SYY * 2 + 320));
    ch = (ch / 256) * 256;
    if (ch < 256) ch = 256;
    if (ch > SX) ch = SX;
    CH = (int)ch;
  }

  char* w = (char*)d_ws;
  f16* Ubuf = (f16*)w;            size_t off = (size_t)nb * CH * SYY * 2;
  float2* MLbuf = (float2*)(w + off); off += (size_t)nb * 32 * CH * 8;
  f16* Fqbuf = (f16*)(w + off);   off += (size_t)nb * 32 * CH * 2;
  f16* X16 = (f16*)(w + off);     off += (size_t)nb * SX * DDIM * 2;
  f16* Y16 = (f16*)(w + off);     off += (size_t)nb * SYY * DDIM * 2;
  f16* Yt16 = (f16*)(w + off);

  for (int b0 = 0; b0 < NBATCH; b0 += nb) {
    int nbc = (NBATCH - b0 < nb) ? (NBATCH - b0) : nb;
    k_prep_x<<<2048, 256, 0, stream>>>(
        (const float4*)(x + (size_t)b0 * SX * DDIM),
        out + (size_t)b0 * SX * 2 * DDIM, (h4_t*)X16,
        (long)nbc * SX * (DDIM / 4));
    dim3 tg(DDIM / 64, SYY / 64, nbc);
    k_trans<<<tg, 256, 0, stream>>>(y + (size_t)b0 * SYY * DDIM, Y16, Yt16);

    for (int i0 = 0; i0 < SX; i0 += CH) {
      int ntm = CH / 256;
      int nblk1 = nbc * ntm * (SYY / 256);
      k_gemm1<<<nblk1, 512, 0, stream>>>(X16, (long)SX * DDIM, i0, DDIM,
                                         Y16, (long)SYY * DDIM, DDIM,
                                         Ubuf, (long)CH * SYY,
                                         MLbuf, CH,
                                         DDIM, ntm, SYY / 256, nblk1);
      long rows_total = (long)nbc * CH;
      k_mlred<<<(unsigned)((rows_total + 255) / 256), 256, 0, stream>>>(
          MLbuf, Fqbuf, CH, rows_total);
      int nblk2 = nbc * ntm * (DDIM / 256);
      k_gemm2<<<nblk2, 512, 0, stream>>>(Ubuf, (long)CH * SYY, 0, SYY,
                                         Yt16, (long)DDIM * SYY, SYY,
                                         out + (size_t)b0 * SX * 2 * DDIM,
                                         (long)SX * 2 * DDIM, i0, 2 * DDIM, DDIM,
                                         Fqbuf, CH,
                                         SYY, ntm, DDIM / 256, nblk2);
    }
  }
}